// Round 7
// baseline (270.715 us; speedup 1.0000x reference)
//
#include <hip/hip_runtime.h>
#include <cstddef>
#include <cstdint>

// ---------------------------------------------------------------------------
// MultiheadSelfAttn (b=4, l=2048, d=768, nh=12, hd=64), softmax over QUERY axis.
// cvt -> fused QKV GEMM -> LN x2 (short8-vectorized) -> stats (r5 structure:
// 128q tiles, single acc, fused V-transpose, Rl in LDS) -> attention out
// (cross-tile pipeline, triple-buffered K/V, counted vmcnt(2)) ->
// final GEMM (64x128 tiles, grid 768 = EXACT 3 blocks/CU, zero tail --
// old 384-block grid was 1.5 blocks/CU, latency-exposed).
// r4 lesson kept: NO double-buffered accumulators (128-reg acc state spills).
// r6 lesson kept: stats 64q-retile regressed; r5 128q structure restored.
// ---------------------------------------------------------------------------

typedef unsigned short u16;
typedef short  bf16x8 __attribute__((ext_vector_type(8)));   // MFMA A/B frag
typedef float  f32x4  __attribute__((ext_vector_type(4)));   // MFMA C/D frag
typedef unsigned short u16x8 __attribute__((ext_vector_type(8)));
typedef unsigned short u16x4 __attribute__((ext_vector_type(4)));

#define B_   4
#define L_   2048
#define D_   768
#define NH_  12
#define HD_  64
#define M_   (B_*L_)
#define SC2  (0.125f * 1.44269504088896f)   // scale * log2(e), folded into qb

__device__ __forceinline__ float ex2(float x) { return __builtin_amdgcn_exp2f(x); }

__device__ __forceinline__ u16 f2bf(float f) {            // RNE
    union { float f; unsigned u; } v; v.f = f;
    unsigned r = v.u + 0x7FFFu + ((v.u >> 16) & 1u);
    return (u16)(r >> 16);
}
__device__ __forceinline__ float bf2f(u16 b) {
    union { unsigned u; float f; } v; v.u = ((unsigned)b) << 16;
    return v.f;
}
__device__ __forceinline__ unsigned fbits(float f) {
    union { float f; unsigned u; } v; v.f = f; return v.u;
}
// pack two f32 -> (bf16(lo) | bf16(hi)<<16), truncation (P>=0, slack ok)
__device__ __forceinline__ unsigned packbf(float lo, float hi) {
    return __builtin_amdgcn_perm(fbits(hi), fbits(lo), 0x07060302u);
}

// async global->LDS, 16B/lane; LDS dest = wave-uniform base + lane*16.
__device__ __forceinline__ void gld16(const void* g, void* l) {
    __builtin_amdgcn_global_load_lds(
        (const __attribute__((address_space(1))) unsigned*)g,
        (__attribute__((address_space(3))) unsigned*)l, 16, 0, 0);
}

// ---------------------------------------------------------------------------
// fp32 -> bf16 bulk convert: x + 4 weights in ONE launch (flat chunk index).
// ---------------------------------------------------------------------------
__global__ __launch_bounds__(256) void cvt_all(
    const float* __restrict__ X,
    const float* __restrict__ W0, const float* __restrict__ W1,
    const float* __restrict__ W2, const float* __restrict__ W3,
    u16* __restrict__ Yx,
    u16* __restrict__ Y0, u16* __restrict__ Y1,
    u16* __restrict__ Y2, u16* __restrict__ Y3)
{
    const int nX8 = (M_ * D_) / 8;      // 786432
    const int nW8 = (D_ * D_) / 8;      // 73728
    int i = blockIdx.x * 256 + threadIdx.x;
    if (i >= nX8 + 4 * nW8) return;
    const float* S; u16* Dst; int off;
    if (i < nX8) { S = X; Dst = Yx; off = i; }
    else {
        int j = i - nX8;
        int w = j / nW8; off = j - w * nW8;
        S   = (w == 0) ? W0 : (w == 1) ? W1 : (w == 2) ? W2 : W3;
        Dst = (w == 0) ? Y0 : (w == 1) ? Y1 : (w == 2) ? Y2 : Y3;
    }
    const float4* xp = (const float4*)S + (size_t)off * 2;
    float4 a = xp[0], b = xp[1];
    u16x8 o;
    o[0] = f2bf(a.x); o[1] = f2bf(a.y); o[2] = f2bf(a.z); o[3] = f2bf(a.w);
    o[4] = f2bf(b.x); o[5] = f2bf(b.y); o[6] = f2bf(b.z); o[7] = f2bf(b.w);
    *((u16x8*)Dst + off) = o;
}

// ---------------------------------------------------------------------------
// Fused QKV GEMM: A[8192,768] x {Wq,Wk,Wv}^T -> bf16. 128x128 tile, BK=32,
// dbuf (1 barrier/iter), BK-swizzled LDS, C^T accumulate, bf16 LDS epilogue.
// ---------------------------------------------------------------------------
__global__ __launch_bounds__(256, 4) void gemm_qkv(
    const u16* __restrict__ A,
    const u16* __restrict__ W0, const u16* __restrict__ W1,
    const u16* __restrict__ W2,
    const float* __restrict__ bk, const float* __restrict__ bv,
    u16* __restrict__ q_o, u16* __restrict__ k_o, u16* __restrict__ v_o)
{
    __shared__ __align__(16) u16 lds[16384];   // [A0|A1|B0|B1] 4x8KB -> Ct 32KB
    __shared__ float bs[128];
    const int tid  = threadIdx.x;
    const int lane = tid & 63, w = tid >> 6;
    const int s    = lane & 15, quad = lane >> 4;
    const int bid  = blockIdx.x;
    const int xcd  = bid & 7, j0 = bid >> 3;       // j0 in 0..143
    const int bm   = (xcd * 8 + j0 / 18) * 128;
    const int sub  = j0 % 18;
    const int seg  = sub / 6;
    const int bn   = (sub % 6) * 128;
    const u16* W = (seg == 0) ? W0 : ((seg == 1) ? W1 : W2);
    u16* OUT = (seg == 0) ? q_o : ((seg == 1) ? k_o : v_o);
    const int mh = (w >> 1) * 64, nh = (w & 1) * 64;
    const int wb = tid & ~63;
    const int cq = quad ^ ((s >> 1) & 3);      // swizzled frag chunk

    if (tid < 128)
        bs[tid] = (seg == 1) ? bk[bn + tid] : ((seg == 2) ? bv[bn + tid] : 0.0f);

    f32x4 acc[4][4];   // [j (n-tile)][i (m-tile)], C^T
    #pragma unroll
    for (int j = 0; j < 4; ++j)
        #pragma unroll
        for (int i = 0; i < 4; ++i) acc[j][i] = (f32x4){0.f, 0.f, 0.f, 0.f};

    {
        int c = tid, r = c >> 2, cs = (c & 3) ^ ((r >> 1) & 3);
        gld16(A + (size_t)(bm + r) * D_ + cs * 8, lds + (size_t)wb * 8);
        gld16(W + (size_t)(bn + r) * D_ + cs * 8, lds + 8192 + (size_t)wb * 8);
        c = tid + 256; r = c >> 2; cs = (c & 3) ^ ((r >> 1) & 3);
        gld16(A + (size_t)(bm + r) * D_ + cs * 8, lds + (size_t)(wb + 256) * 8);
        gld16(W + (size_t)(bn + r) * D_ + cs * 8, lds + 8192 + (size_t)(wb + 256) * 8);
    }
    __syncthreads();

    for (int t = 0; t < 24; ++t) {
        const u16* Ab = lds + (t & 1) * 4096;
        const u16* Bb = lds + 8192 + (t & 1) * 4096;
        if (t < 23) {
            const int k0 = (t + 1) * 32;
            u16* Ad = lds + ((t + 1) & 1) * 4096;
            u16* Bd = lds + 8192 + ((t + 1) & 1) * 4096;
            int c = tid, r = c >> 2, cs = (c & 3) ^ ((r >> 1) & 3);
            gld16(A + (size_t)(bm + r) * D_ + k0 + cs * 8, Ad + (size_t)wb * 8);
            gld16(W + (size_t)(bn + r) * D_ + k0 + cs * 8, Bd + (size_t)wb * 8);
            c = tid + 256; r = c >> 2; cs = (c & 3) ^ ((r >> 1) & 3);
            gld16(A + (size_t)(bm + r) * D_ + k0 + cs * 8, Ad + (size_t)(wb + 256) * 8);
            gld16(W + (size_t)(bn + r) * D_ + k0 + cs * 8, Bd + (size_t)(wb + 256) * 8);
        }
        bf16x8 af[4], bf[4];
        #pragma unroll
        for (int i = 0; i < 4; ++i)
            af[i] = *(const bf16x8*)(Ab + (mh + i * 16 + s) * 32 + cq * 8);
        #pragma unroll
        for (int j = 0; j < 4; ++j)
            bf[j] = *(const bf16x8*)(Bb + (nh + j * 16 + s) * 32 + cq * 8);
        #pragma unroll
        for (int j = 0; j < 4; ++j)
            #pragma unroll
            for (int i = 0; i < 4; ++i)
                acc[j][i] = __builtin_amdgcn_mfma_f32_16x16x32_bf16(
                    bf[j], af[i], acc[j][i], 0, 0, 0);   // C^T: rows=n, cols=m
        __syncthreads();
    }
    // epilogue: bf16 + bias -> Ct[m][128] (chunk ^ (m&15)) -> coalesced store
    u16* Ct = lds;
    #pragma unroll
    for (int j = 0; j < 4; ++j) {
        const int n0 = nh + j * 16 + quad * 4;
        const f32x4 b4 = *(const f32x4*)(bs + n0);
        const int cn = n0 >> 3, off = n0 & 7;
        #pragma unroll
        for (int i = 0; i < 4; ++i) {
            const int m = mh + i * 16 + s;
            u16x4 ov;
            #pragma unroll
            for (int r = 0; r < 4; ++r) ov[r] = f2bf(acc[j][i][r] + b4[r]);
            *(u16x4*)(Ct + m * 128 + ((cn ^ (m & 15)) * 8) + off) = ov;
        }
    }
    __syncthreads();
    {
        const int m = tid >> 1, half = tid & 1;
        u16* dst = OUT + (size_t)(bm + m) * D_ + bn + half * 64;
        #pragma unroll
        for (int cc = 0; cc < 8; ++cc) {
            const int cn = half * 8 + cc;
            u16x8 v = *(const u16x8*)(Ct + m * 128 + ((cn ^ (m & 15)) * 8));
            *(u16x8*)(dst + cc * 8) = v;
        }
    }
}

// ---------------------------------------------------------------------------
// Final GEMM: out = ob @ Wo^T + bo + x (fp32 out). 64x128 tile, BK=32, dbuf.
// Grid 768 = 8 XCD x (16 bm x 6 bn) -> EXACTLY 3 blocks/CU co-resident
// (old 128x128/384-block grid was 1.5 blocks/CU: latency-exposed, no
// cross-block cover for the per-iter vmcnt(0) barrier drain).
// Per wave: 32x64 output, acc[4][2] (32 VGPR). LDS 24 KB.
// ---------------------------------------------------------------------------
__global__ __launch_bounds__(256, 3) void gemm_final(
    const u16* __restrict__ A, const u16* __restrict__ W,
    const float* __restrict__ bias, const float* __restrict__ resid,
    float* __restrict__ outf)
{
    __shared__ __align__(16) u16 lds[12288];   // A0|A1 (2x2048) B0|B1 (2x4096)
    const int tid  = threadIdx.x;
    const int lane = tid & 63, w = tid >> 6;
    const int s    = lane & 15, quad = lane >> 4;
    const int bid  = blockIdx.x;
    const int xcd  = bid & 7, j0 = bid >> 3;       // j0 in 0..95
    const int bm   = (xcd * 16 + j0 / 6) * 64;     // 128 m-panels of 64
    const int bn   = (j0 % 6) * 128;
    const int mh   = (w >> 1) * 32, nh = (w & 1) * 64;
    const int wb   = tid & ~63;
    const int cq   = quad ^ ((s >> 1) & 3);
    f32x4 acc[4][2];
    #pragma unroll
    for (int j = 0; j < 4; ++j)
        #pragma unroll
        for (int i = 0; i < 2; ++i) acc[j][i] = (f32x4){0.f, 0.f, 0.f, 0.f};

    {
        int c = tid, r = c >> 2, cs = (c & 3) ^ ((r >> 1) & 3);
        gld16(A + (size_t)(bm + r) * D_ + cs * 8, lds + (size_t)wb * 8);
        gld16(W + (size_t)(bn + r) * D_ + cs * 8, lds + 4096 + (size_t)wb * 8);
        c = tid + 256; r = c >> 2; cs = (c & 3) ^ ((r >> 1) & 3);
        gld16(W + (size_t)(bn + r) * D_ + cs * 8, lds + 4096 + (size_t)(wb + 256) * 8);
    }
    __syncthreads();

    for (int t = 0; t < 24; ++t) {
        const u16* Ab = lds + (t & 1) * 2048;
        const u16* Bb = lds + 4096 + (t & 1) * 4096;
        if (t < 23) {
            const int k0 = (t + 1) * 32;
            u16* Ad = lds + ((t + 1) & 1) * 2048;
            u16* Bd = lds + 4096 + ((t + 1) & 1) * 4096;
            int c = tid, r = c >> 2, cs = (c & 3) ^ ((r >> 1) & 3);
            gld16(A + (size_t)(bm + r) * D_ + k0 + cs * 8, Ad + (size_t)wb * 8);
            gld16(W + (size_t)(bn + r) * D_ + k0 + cs * 8, Bd + (size_t)wb * 8);
            c = tid + 256; r = c >> 2; cs = (c & 3) ^ ((r >> 1) & 3);
            gld16(W + (size_t)(bn + r) * D_ + k0 + cs * 8, Bd + (size_t)(wb + 256) * 8);
        }
        bf16x8 af[2], bf[4];
        #pragma unroll
        for (int i = 0; i < 2; ++i)
            af[i] = *(const bf16x8*)(Ab + (mh + i * 16 + s) * 32 + cq * 8);
        #pragma unroll
        for (int j = 0; j < 4; ++j)
            bf[j] = *(const bf16x8*)(Bb + (nh + j * 16 + s) * 32 + cq * 8);
        #pragma unroll
        for (int j = 0; j < 4; ++j)
            #pragma unroll
            for (int i = 0; i < 2; ++i)
                acc[j][i] = __builtin_amdgcn_mfma_f32_16x16x32_bf16(
                    bf[j], af[i], acc[j][i], 0, 0, 0);
        __syncthreads();
    }
    #pragma unroll
    for (int j = 0; j < 4; ++j) {
        const int n0 = nh + j * 16 + quad * 4;
        const float4 b4 = *(const float4*)(bias + bn + n0);
        #pragma unroll
        for (int i = 0; i < 2; ++i) {
            const int m = mh + i * 16 + s;
            const size_t base = (size_t)(bm + m) * D_ + bn + n0;
            const float4 rs = *(const float4*)(resid + base);
            float4 o;
            o.x = acc[j][i][0] + b4.x + rs.x;
            o.y = acc[j][i][1] + b4.y + rs.y;
            o.z = acc[j][i][2] + b4.z + rs.z;
            o.w = acc[j][i][3] + b4.w + rs.w;
            *(float4*)(outf + base) = o;
        }
    }
}

// ---------------------------------------------------------------------------
// Row LayerNorm (pop var, eps 1e-5) * gamma * scale, bf16 in -> bf16 out.
// VECTORIZED (G13): 8 rows/block, 32 lanes/row, 3x u16x8 per lane (24 elems),
// 32-lane shfl_xor reduce (no LDS). Both q (SC2) and k in one launch (grid.y).
// ---------------------------------------------------------------------------
__global__ __launch_bounds__(256) void ln2_bf16(
    const u16* __restrict__ Q, const u16* __restrict__ K,
    const float* __restrict__ gq, const float* __restrict__ gk,
    u16* __restrict__ Yq, u16* __restrict__ Yk)
{
    const int which = blockIdx.y;
    const int rowi  = threadIdx.x >> 5;          // 0..7
    const int l32   = threadIdx.x & 31;
    const int row   = blockIdx.x * 8 + rowi;
    const u16* x = (which ? K : Q) + (size_t)row * D_ + l32 * 24;
    const float* gamma = (which ? gk : gq) + l32 * 24;
    u16* Y = (which ? Yk : Yq) + (size_t)row * D_ + l32 * 24;
    const float scale = which ? 1.0f : (float)SC2;

    u16x8 vv[3];
    float f[24];
    float lsum = 0.f, lsq = 0.f;
    #pragma unroll
    for (int e = 0; e < 3; ++e) {
        vv[e] = *(const u16x8*)(x + e * 8);
        #pragma unroll
        for (int k = 0; k < 8; ++k) {
            float t = bf2f(vv[e][k]);
            f[e * 8 + k] = t; lsum += t; lsq += t * t;
        }
    }
    #pragma unroll
    for (int off = 16; off > 0; off >>= 1) {     // 32-lane group reduce
        lsum += __shfl_xor(lsum, off);
        lsq  += __shfl_xor(lsq,  off);
    }
    const float mu  = lsum * (1.0f / D_);
    const float var = lsq * (1.0f / D_) - mu * mu;
    const float inv = rsqrtf(var + 1e-5f) * scale;
    #pragma unroll
    for (int e = 0; e < 3; ++e) {
        const float4 ga = *(const float4*)(gamma + e * 8);
        const float4 gb = *(const float4*)(gamma + e * 8 + 4);
        u16x8 o;
        o[0] = f2bf((f[e*8+0] - mu) * inv * ga.x);
        o[1] = f2bf((f[e*8+1] - mu) * inv * ga.y);
        o[2] = f2bf((f[e*8+2] - mu) * inv * ga.z);
        o[3] = f2bf((f[e*8+3] - mu) * inv * ga.w);
        o[4] = f2bf((f[e*8+4] - mu) * inv * gb.x);
        o[5] = f2bf((f[e*8+5] - mu) * inv * gb.y);
        o[6] = f2bf((f[e*8+6] - mu) * inv * gb.z);
        o[7] = f2bf((f[e*8+7] - mu) * inv * gb.w);
        *(u16x8*)(Y + e * 8) = o;
    }
}

// ---------------------------------------------------------------------------
// Pass A: per-key l = sum_q exp2(s~[q,k]) (NO max: QK-norm bounds scores).
// r5 structure (best total): 128q tiles, single acc[4][4], Qs dbuf, setprio.
// V-transpose (+1/l fold, PV key-permutation) FUSED at end, reusing Qs[0]
// as Ts; normalizers stay in LDS (rls). 768 = 8 XCD x (6 bh x 16 k-blocks).
// ---------------------------------------------------------------------------
__global__ __launch_bounds__(256, 3) void attn_stats(
    const u16* __restrict__ Qb, const u16* __restrict__ Kb,
    const u16* __restrict__ Vb, u16* __restrict__ Vt)
{
    __shared__ __align__(16) u16 Ks[128 * 64];       // 16 KB
    __shared__ __align__(16) u16 Qs[2][128 * 64];    // 32 KB dbuf (-> Ts)
    __shared__ float lbuf[4][64];
    __shared__ float rls[128];
    const int tid  = threadIdx.x;
    const int lane = tid & 63, w = tid >> 6;
    const int s    = lane & 15, quad = lane >> 4;
    const int s7   = s & 7;
    const int bid  = blockIdx.x;
    const int xcd  = bid & 7, j0 = bid >> 3;       // j0 in 0..95
    const int bh   = xcd * 6 + j0 / 16;
    const int kbase = (j0 % 16) * 128;
    const int b    = bh / NH_, h = bh % NH_;
    const u16* Qg = Qb + (size_t)b * L_ * D_ + h * HD_;
    const u16* Kg = Kb + (size_t)b * L_ * D_ + h * HD_;
    const int mh = (w >> 1) * 64;   // key half
    const int nh = (w & 1) * 64;    // query half
    const int wb = tid & ~63;

    #pragma unroll
    for (int c0 = 0; c0 < 1024; c0 += 256) {
        int c = c0 + tid, r = c >> 3, cc = (c & 7) ^ (r & 7);
        gld16(Kg + (size_t)(kbase + r) * D_ + cc * 8, Ks + (size_t)(c0 + wb) * 8);
        gld16(Qg + (size_t)r * D_ + cc * 8, Qs[0] + (size_t)(c0 + wb) * 8);
    }
    __syncthreads();
    bf16x8 kf[2][4];
    #pragma unroll
    for (int kk = 0; kk < 2; ++kk)
        #pragma unroll
        for (int i = 0; i < 4; ++i)
            kf[kk][i] = *(const bf16x8*)(Ks + (mh + i * 16 + s) * 64 +
                                         ((kk * 4 + quad) ^ s7) * 8);
    float lacc[4][4];
    #pragma unroll
    for (int i = 0; i < 4; ++i)
        #pragma unroll
        for (int r = 0; r < 4; ++r) lacc[i][r] = 0.f;

    for (int t = 0; t < 16; ++t) {
        if (t < 15) {
            const int qn = (t + 1) * 128;
            u16* Qd = Qs[(t + 1) & 1];
            #pragma unroll
            for (int c0 = 0; c0 < 1024; c0 += 256) {
                int c = c0 + tid, r = c >> 3, cc = (c & 7) ^ (r & 7);
                gld16(Qg + (size_t)(qn + r) * D_ + cc * 8, Qd + (size_t)(c0 + wb) * 8);
            }
        }
        const u16* Qt = Qs[t & 1];
        f32x4 acc[4][4];
        #pragma unroll
        for (int i = 0; i < 4; ++i)
            #pragma unroll
            for (int j = 0; j < 4; ++j) acc[i][j] = (f32x4){0.f, 0.f, 0.f, 0.f};
        #pragma unroll
        for (int kk = 0; kk < 2; ++kk) {
            bf16x8 bf[4];
            #pragma unroll
            for (int j = 0; j < 4; ++j)
                bf[j] = *(const bf16x8*)(Qt + (nh + j * 16 + s) * 64 +
                                         ((kk * 4 + quad) ^ s7) * 8);
            __builtin_amdgcn_s_setprio(1);
            #pragma unroll
            for (int i = 0; i < 4; ++i)
                #pragma unroll
                for (int j = 0; j < 4; ++j)
                    acc[i][j] = __builtin_amdgcn_mfma_f32_16x16x32_bf16(
                        kf[kk][i], bf[j], acc[i][j], 0, 0, 0);
            __builtin_amdgcn_s_setprio(0);
        }
        #pragma unroll
        for (int i = 0; i < 4; ++i)
            #pragma unroll
            for (int r = 0; r < 4; ++r) {
                float l0 = ex2(acc[i][0][r]) + ex2(acc[i][1][r]);
                float l1 = ex2(acc[i][2][r]) + ex2(acc[i][3][r]);
                lacc[i][r] += l0 + l1;
            }
        __syncthreads();
    }
    #pragma unroll
    for (int i = 0; i < 4; ++i)
        #pragma unroll
        for (int r = 0; r < 4; ++r) {
            float v = lacc[i][r];
            #pragma unroll
            for (int d2 = 1; d2 < 16; d2 <<= 1) v += __shfl_xor(v, d2);
            lacc[i][r] = v;
        }
    if (s == 0) {
        #pragma unroll
        for (int i = 0; i < 4; ++i)
            #pragma unroll
            for (int r = 0; r < 4; ++r)
                lbuf[w][i * 16 + quad * 4 + r] = lacc[i][r];
    }
    __syncthreads();
    if (tid < 128) {
        int kh = tid >> 6, kl = tid & 63;
        float l = lbuf[kh * 2][kl] + lbuf[kh * 2 + 1][kl];
        rls[tid] = 1.0f / l;
    }
    __syncthreads();

    // ---- fused V transpose: scale by 1/l, PV key-permutation, 2 x 64 rows.
    // Ts reuses Qs[0] (dead after t=15; barriers above order the reuse).
    u16 (*Ts)[72] = (u16 (*)[72])(&Qs[0][0]);
    for (int half = 0; half < 2; ++half) {
        const int l0g = kbase + half * 64;
        for (int c = tid; c < 512; c += 256) {
            int r = c >> 3, cc = c & 7;
            u16x8 val = *(const u16x8*)(Vb + (size_t)(b * L_ + l0g + r) * D_ +
                                        h * HD_ + cc * 8);
            const float rl = rls[half * 64 + r];
            #pragma unroll
            for (int e = 0; e < 8; ++e) val[e] = f2bf(bf2f(val[e]) * rl);
            *(u16x8*)(&Ts[r][cc * 8]) = val;
        }
        __syncthreads();
        const int d = tid >> 2, lc = (tid & 3) * 16;
        u16 tmp[16];
        #pragma unroll
        for (int e = 0; e < 16; ++e) tmp[e] = Ts[lc + e][d];
        u16* dst = Vt + ((size_t)bh * HD_ + d) * L_ + l0g + (lc & 32) +
                   ((lc >> 4) & 1) * 4;
        #pragma unroll
        for (int qd = 0; qd < 4; ++qd) {
            u16x4 o;
            #pragma unroll
            for (int e = 0; e < 4; ++e) o[e] = tmp[qd * 4 + e];
            *(u16x4*)(dst + qd * 8) = o;
        }
        __syncthreads();
    }
}

// ---------------------------------------------------------------------------
// Pass B: O^T = V'^T · P^T, P = exp2(s~) in registers. 128 q/block,
// wave = 64 keys x 32-q slice. CROSS-TILE SOFTWARE PIPELINE:
//   iter t:  prefetch(t+2) | exp(t)->pk | S-MFMA(t+1) [indep of exp(t)]
//            | PV-MFMA(t)  | vmcnt(2)+barrier
// Two acc_s states (static names, rule-#20 safe) alternate via unroll-by-2.
// Stage order per tile: K x2 then V x2 -> steady-state wait = vmcnt(2)
// (drains V(t+1)+K(t+2), leaves V(t+2) in flight). Triple-buffered K/V.
// setprio only around PV (S cluster left free for exp interleave).
// ---------------------------------------------------------------------------
__global__ __launch_bounds__(256, 3) void attn_out(
    const u16* __restrict__ Qb, const u16* __restrict__ Kb,
    const u16* __restrict__ Vt, u16* __restrict__ Ob)
{
    __shared__ __align__(16) u16 Ks[3][64 * 64];   // 24 KB triple-buffer
    __shared__ __align__(16) u16 Vts[3][64 * 64];  // 24 KB triple-buffer
    const int tid  = threadIdx.x;
    const int lane = tid & 63, w = tid >> 6;
    const int s    = lane & 15, quad = lane >> 4;
    const int s7   = s & 7;
    const int bid  = blockIdx.x;
    const int xcd  = bid & 7, j0 = bid >> 3;       // j0 in 0..95
    const int bh   = xcd * 6 + j0 / 16;
    const int qbase = (j0 % 16) * 128;
    const int b    = bh / NH_, h = bh % NH_;
    const int qw   = w * 32;                        // this wave's 32-q slice
    const u16* Qg = Qb + (size_t)b * L_ * D_ + h * HD_;
    const u16* Kg = Kb + (size_t)b * L_ * D_ + h * HD_;
    const u16* Vg = Vt + (size_t)bh * HD_ * L_;
    const int wb = tid & ~63;

    // Q frags direct global->reg (oldest in vm queue; drained by prologue wait)
    bf16x8 qf[2][2];
    #pragma unroll
    for (int kk = 0; kk < 2; ++kk)
        #pragma unroll
        for (int j = 0; j < 2; ++j)
            qf[kk][j] = *(const bf16x8*)(
                Qg + (size_t)(qbase + qw + j * 16 + s) * D_ + (kk * 4 + quad) * 8);

    // stage K0,K1 then V0,V1 (queue order: drain thru V0+K1, leave V1 x2)
    {
        int c = tid, r = c >> 3, cc = (c & 7) ^ (r & 7);
        int c2 = tid + 256, r2 = c2 >> 3, cc2 = (c2 & 7) ^ (r2 & 7);
        gld16(Kg + (size_t)r * D_ + cc * 8,          Ks[0] + (size_t)wb * 8);
        gld16(Kg + (size_t)r2 * D_ + cc2 * 8,        Ks[0] + (size_t)(wb + 256) * 8);
        gld16(Kg + (size_t)(64 + r) * D_ + cc * 8,   Ks[1] + (size_t)wb * 8);
        gld16(Kg + (size_t)(64 + r2) * D_ + cc2 * 8, Ks[1] + (size_t)(wb + 256) * 8);
        gld16(Vg + (size_t)r * L_ + cc * 8,          Vts[0] + (size_t)wb * 8);
        gld16(Vg + (size_t)r2 * L_ + cc2 * 8,        Vts[0] + (size_t)(wb + 256) * 8);
        gld16(Vg + (size_t)r * L_ + 64 + cc * 8,     Vts[1] + (size_t)wb * 8);
        gld16(Vg + (size_t)r2 * L_ + 64 + cc2 * 8,   Vts[1] + (size_t)(wb + 256) * 8);
    }
    asm volatile("s_waitcnt vmcnt(2)" ::: "memory");   // leave V1 x2 in flight
    __builtin_amdgcn_s_barrier();

    f32x4 acc_o[4][2];
    #pragma unroll
    for (int i = 0; i < 4; ++i)
        #pragma unroll
        for (int j = 0; j < 2; ++j) acc_o[i][j] = (f32x4){0.f, 0.f, 0.f, 0.f};

    // ---- prologue: S(0) -> acc_s0 ----
    f32x4 acc_s0[4][2], acc_s1[4][2];
    #pragma unroll
    for (int i = 0; i < 4; ++i)
        #pragma unroll
        for (int j = 0; j < 2; ++j) acc_s0[i][j] = (f32x4){0.f, 0.f, 0.f, 0.f};
    #pragma unroll
    for (int kk = 0; kk < 2; ++kk) {
        bf16x8 kfr[4];
        #pragma unroll
        for (int i = 0; i < 4; ++i)
            kfr[i] = *(const bf16x8*)(Ks[0] + (i * 16 + s) * 64 +
                                      ((kk * 4 + quad) ^ s7) * 8);
        #pragma unroll
        for (int i = 0; i < 4; ++i)
            #pragma unroll
            for (int j = 0; j < 2; ++j)
                acc_s0[i][j] = __builtin_amdgcn_mfma_f32_16x16x32_bf16(
                    kfr[i], qf[kk][j], acc_s0[i][j], 0, 0, 0);
    }

// Tile body. ACCC: acc_s state holding S(TT). ACCN: state to fill with S(TT+1).
// DO_PF: prefetch tile TT+2.  DO_S: compute S(TT+1).  WMODE: 2 / 0 / -1.
#define ATTN_TILE(ACCC, ACCN, TT, DO_PF, DO_S, WMODE)                          \
    do {                                                                       \
        const int t_ = (TT);                                                   \
        if (DO_PF) {                                                           \
            const int pi_ = (t_ + 2) % 3;                                      \
            const int kn_ = (t_ + 2) * 64;                                     \
            u16* Kd_ = Ks[pi_]; u16* Vd_ = Vts[pi_];                           \
            int c_ = tid, r_ = c_ >> 3, cc_ = (c_ & 7) ^ (r_ & 7);             \
            int c2_ = tid + 256, r2_ = c2_ >> 3, cc2_ = (c2_ & 7) ^ (r2_ & 7); \
            gld16(Kg + (size_t)(kn_ + r_) * D_ + cc_ * 8,                      \
                  Kd_ + (size_t)wb * 8);                                       \
            gld16(Kg + (size_t)(kn_ + r2_) * D_ + cc2_ * 8,                    \
                  Kd_ + (size_t)(wb + 256) * 8);                               \
            gld16(Vg + (size_t)r_ * L_ + kn_ + cc_ * 8,                        \
                  Vd_ + (size_t)wb * 8);                                       \
            gld16(Vg + (size_t)r2_ * L_ + kn_ + cc2_ * 8,                      \
                  Vd_ + (size_t)(wb + 256) * 8);                               \
        }                                                                      \
        /* exp(TT): ACCC -> pk (VALU; independent of S(TT+1) MFMAs) */         \
        unsigned pk_[4][2][2];                                                 \
        _Pragma("unroll")                                                      \
        for (int i = 0; i < 4; ++i)                                            \
            _Pragma("unroll")                                                  \
            for (int j = 0; j < 2; ++j) {                                      \
                float p0_ = ex2(ACCC[i][j][0]), p1_ = ex2(ACCC[i][j][1]);      \
                float p2_ = ex2(ACCC[i][j][2]), p3_ = ex2(ACCC[i][j][3]);      \
                pk_[i][j][0] = packbf(p0_, p1_);                               \
                pk_[i][j][1] = packbf(p2_, p3_);                               \
            }                                                                  \
        if (DO_S) {                                                            \
            const u16* Kt_ = Ks[(t_ + 1) % 3];                                 \
            _Pragma("unroll")                                                  \
            for (int i = 0; i < 4; ++i)                                        \
                _Pragma("unroll")                                              \
                for (int j = 0; j < 2; ++j)                                    \
                    ACCN[i][j] = (f32x4){0.f, 0.f, 0.f, 0.f};                  \
            _Pragma("unroll")                                                  \
            for (int kk = 0; kk < 2; ++kk) {                                   \
                bf16x8 kfr_[4];                                                \
                _Pragma("unroll")                                              \
                for (int i = 0; i < 4; ++i)                                    \
                    kfr_[i] = *(const bf16x8*)(Kt_ + (i * 16 + s) * 64 +       \
                                               ((kk * 4 + quad) ^ s7) * 8);    \
                _Pragma("unroll")                                              \
                for (int i = 0; i < 4; ++i)                                    \
                    _Pragma("unroll")                                          \
                    for (int j = 0; j < 2; ++j)                                \
                        ACCN[i][j] = __builtin_amdgcn_mfma_f32_16x16x32_bf16(  \
                            kfr_[i], qf[kk][j], ACCN[i][j], 0, 0, 0);          \
            }                                                                  \
        }                                                                      \
        /* PV(TT) */                                                           \
        {                                                                      \
            const u16* Vtt_ = Vts[t_ % 3];                                     \
            _Pragma("unroll")                                                  \
            for (int kk = 0; kk < 2; ++kk) {                                   \
                bf16x8 av_[4];                                                 \
                _Pragma("unroll")                                              \
                for (int i = 0; i < 4; ++i)                                    \
                    av_[i] = *(const bf16x8*)(Vtt_ + (i * 16 + s) * 64 +       \
                                              ((kk * 4 + quad) ^ s7) * 8);     \
                __builtin_amdgcn_s_setprio(1);                                 \
                _Pragma("unroll")                                              \
                for (int j = 0; j < 2; ++j) {                                  \
                    union { unsigned u[4]; bf16x8 v; } bu_;                    \
                    bu_.u[0] = pk_[2 * kk][j][0];                              \
                    bu_.u[1] = pk_[2 * kk][j][1];                              \
                    bu_.u[2] = pk_[2 * kk + 1][j][0];                          \
                    bu_.u[3] = pk_[2 * kk + 1][j][1];                          \
                    _Pragma("unroll")                                          \
                    for (int i = 0; i < 4; ++i)                                \
                        acc_o[i][j] = __builtin_amdgcn_mfma_f32_16x16x32_bf16( \
                            av_[i], bu_.v, acc_o[i][j], 0, 0, 0);              \
                }                                                              \
                __builtin_amdgcn_s_setprio(0);                                 \
            }                                                                  \
        }                                                                      \
        if (WMODE == 2) {                                                      \
            asm volatile("s_waitcnt vmcnt(2)" ::: "memory");                   \
            __builtin_amdgcn_s_barrier();                                      \
        } else if (WMODE == 0) {                                               \
            asm volatile("s_waitcnt vmcnt(0)" ::: "memory");                   \
            __builtin_amdgcn_s_barrier();                                      \
        }                                                                      \
    } while (0)

    for (int t = 0; t < 30; t += 2) {
        ATTN_TILE(acc_s0, acc_s1, t,     1, 1, 2);
        ATTN_TILE(acc_s1, acc_s0, t + 1, 1, 1, 2);
    }
    ATTN_TILE(acc_s0, acc_s1, 30, 0, 1, 0);   // no prefetch; drain; S(31)
    ATTN_TILE(acc_s1, acc_s0, 31, 0, 0, -1);  // tail: exp(31)+PV(31) only
#undef ATTN_TILE

    __syncthreads();
    // ---- epilogue: O^T -> Ks[0..1] as [128 q][64 d] (swizzled) -> store
    u16* Ep = (u16*)Ks;
    #pragma unroll
    for (int i = 0; i < 4; ++i) {
        const int dchunk = i * 2 + (quad >> 1), doff = (quad & 1) * 4;
        #pragma unroll
        for (int j = 0; j < 2; ++j) {
            const int q = qw + j * 16 + s;
            u16x4 ov;
            #pragma unroll
            for (int r = 0; r < 4; ++r) ov[r] = f2bf(acc_o[i][j][r]);
            *(u16x4*)(Ep + q * 64 + (dchunk ^ s7) * 8 + doff) = ov;
        }
    }
    __syncthreads();
    {
        const int q = tid >> 1, half = tid & 1, q7 = q & 7;
        u16* dst = Ob + (size_t)(b * L_ + qbase + q) * D_ + h * HD_ + half * 32;
        #pragma unroll
        for (int c = 0; c < 4; ++c) {
            const int cn = half * 4 + c;
            u16x8 v = *(const u16x8*)(Ep + q * 64 + ((cn ^ q7) * 8));
            *(u16x8*)(dst + c * 8) = v;
        }
    }
}

// ---------------------------------------------------------------------------
extern "C" void kernel_launch(void* const* d_in, const int* in_sizes, int n_in,
                              void* d_out, int out_size, void* d_ws, size_t ws_size,
                              hipStream_t stream)
{
    const float* x  = (const float*)d_in[0];
    const float* Wq = (const float*)d_in[1];
    const float* Wk = (const float*)d_in[2];
    const float* bk = (const float*)d_in[3];
    const float* Wv = (const float*)d_in[4];
    const float* bv = (const float*)d_in[5];
    const float* gq = (const float*)d_in[6];
    const float* gk = (const float*)d_in[7];
    const float* Wo = (const float*)d_in[8];
    const float* bo = (const float*)d_in[9];
    float* out = (float*)d_out;

    char* p = (char*)d_ws;
    u16* xb   = (u16*)p;  p += (size_t)M_ * D_ * 2;
    u16* qpre = (u16*)p;  p += (size_t)M_ * D_ * 2;   // ob aliases after LN
    u16* kpre = (u16*)p;  p += (size_t)M_ * D_ * 2;   // vt aliases after LN
    u16* vb   = (u16*)p;  p += (size_t)M_ * D_ * 2;
    u16* qb   = (u16*)p;  p += (size_t)M_ * D_ * 2;
    u16* kb   = (u16*)p;  p += (size_t)M_ * D_ * 2;
    u16* wqb  = (u16*)p;  p += (size_t)D_ * D_ * 2;
    u16* wkb  = (u16*)p;  p += (size_t)D_ * D_ * 2;
    u16* wvb  = (u16*)p;  p += (size_t)D_ * D_ * 2;
    u16* wob  = (u16*)p;  p += (size_t)D_ * D_ * 2;
    u16* ob = qpre;   // dead after LN
    u16* vt = kpre;   // dead after LN

    const int nTot8 = (M_ * D_ + 4 * D_ * D_) / 8;    // 1,081,344
    cvt_all<<<(nTot8 + 255) / 256, 256, 0, stream>>>(
        x, Wq, Wk, Wv, Wo, xb, wqb, wkb, wvb, wob);

    gemm_qkv<<<1152, 256, 0, stream>>>(
        xb, wqb, wkb, wvb, bk, bv, qpre, kpre, vb);

    ln2_bf16<<<dim3(M_ / 8, 2), 256, 0, stream>>>(qpre, kpre, gq, gk, qb, kb);

    attn_stats<<<768, 256, 0, stream>>>(qb, kb, vb, vt);   // + fused V-transpose
    attn_out<<<768, 256, 0, stream>>>(qb, kb, vt, ob);

    gemm_final<<<768, 256, 0, stream>>>(ob, wob, bo, x, out);
}

// Round 8
// 264.871 us; speedup vs baseline: 1.0221x; 1.0221x over previous
//
#include <hip/hip_runtime.h>
#include <cstddef>
#include <cstdint>

// ---------------------------------------------------------------------------
// MultiheadSelfAttn (b=4, l=2048, d=768, nh=12, hd=64), softmax over QUERY axis.
// BEST-MEASURED COMPOSITION (delta algebra r5/r6/r7):
//   r5 base: stats 128q-tile single-acc + fused V-transpose (Rl in LDS),
//            gemm_final 128x128 / 384 blocks, attn_out cross-tile pipeline.
//   + vectorized LN (only delta with negative sign: ~-4us).
// Lessons pinned: r4 = no double-buffered accumulators (spill -> 650MB scratch);
// r6 = stats 64q-retile +7us; r7 = final 64x128 retile +7us (A-reuse halved).
// ---------------------------------------------------------------------------

typedef unsigned short u16;
typedef short  bf16x8 __attribute__((ext_vector_type(8)));   // MFMA A/B frag
typedef float  f32x4  __attribute__((ext_vector_type(4)));   // MFMA C/D frag
typedef unsigned short u16x8 __attribute__((ext_vector_type(8)));
typedef unsigned short u16x4 __attribute__((ext_vector_type(4)));

#define B_   4
#define L_   2048
#define D_   768
#define NH_  12
#define HD_  64
#define M_   (B_*L_)
#define SC2  (0.125f * 1.44269504088896f)   // scale * log2(e), folded into qb

__device__ __forceinline__ float ex2(float x) { return __builtin_amdgcn_exp2f(x); }

__device__ __forceinline__ u16 f2bf(float f) {            // RNE
    union { float f; unsigned u; } v; v.f = f;
    unsigned r = v.u + 0x7FFFu + ((v.u >> 16) & 1u);
    return (u16)(r >> 16);
}
__device__ __forceinline__ float bf2f(u16 b) {
    union { unsigned u; float f; } v; v.u = ((unsigned)b) << 16;
    return v.f;
}
__device__ __forceinline__ unsigned fbits(float f) {
    union { float f; unsigned u; } v; v.f = f; return v.u;
}
// pack two f32 -> (bf16(lo) | bf16(hi)<<16), truncation (P>=0, slack ok)
__device__ __forceinline__ unsigned packbf(float lo, float hi) {
    return __builtin_amdgcn_perm(fbits(hi), fbits(lo), 0x07060302u);
}

// async global->LDS, 16B/lane; LDS dest = wave-uniform base + lane*16.
__device__ __forceinline__ void gld16(const void* g, void* l) {
    __builtin_amdgcn_global_load_lds(
        (const __attribute__((address_space(1))) unsigned*)g,
        (__attribute__((address_space(3))) unsigned*)l, 16, 0, 0);
}

// ---------------------------------------------------------------------------
// fp32 -> bf16 bulk convert: x + 4 weights in ONE launch (flat chunk index).
// ---------------------------------------------------------------------------
__global__ __launch_bounds__(256) void cvt_all(
    const float* __restrict__ X,
    const float* __restrict__ W0, const float* __restrict__ W1,
    const float* __restrict__ W2, const float* __restrict__ W3,
    u16* __restrict__ Yx,
    u16* __restrict__ Y0, u16* __restrict__ Y1,
    u16* __restrict__ Y2, u16* __restrict__ Y3)
{
    const int nX8 = (M_ * D_) / 8;      // 786432
    const int nW8 = (D_ * D_) / 8;      // 73728
    int i = blockIdx.x * 256 + threadIdx.x;
    if (i >= nX8 + 4 * nW8) return;
    const float* S; u16* Dst; int off;
    if (i < nX8) { S = X; Dst = Yx; off = i; }
    else {
        int j = i - nX8;
        int w = j / nW8; off = j - w * nW8;
        S   = (w == 0) ? W0 : (w == 1) ? W1 : (w == 2) ? W2 : W3;
        Dst = (w == 0) ? Y0 : (w == 1) ? Y1 : (w == 2) ? Y2 : Y3;
    }
    const float4* xp = (const float4*)S + (size_t)off * 2;
    float4 a = xp[0], b = xp[1];
    u16x8 o;
    o[0] = f2bf(a.x); o[1] = f2bf(a.y); o[2] = f2bf(a.z); o[3] = f2bf(a.w);
    o[4] = f2bf(b.x); o[5] = f2bf(b.y); o[6] = f2bf(b.z); o[7] = f2bf(b.w);
    *((u16x8*)Dst + off) = o;
}

// ---------------------------------------------------------------------------
// Fused QKV GEMM: A[8192,768] x {Wq,Wk,Wv}^T -> bf16. 128x128 tile, BK=32,
// dbuf (1 barrier/iter), BK-swizzled LDS, C^T accumulate, bf16 LDS epilogue.
// ---------------------------------------------------------------------------
__global__ __launch_bounds__(256, 4) void gemm_qkv(
    const u16* __restrict__ A,
    const u16* __restrict__ W0, const u16* __restrict__ W1,
    const u16* __restrict__ W2,
    const float* __restrict__ bk, const float* __restrict__ bv,
    u16* __restrict__ q_o, u16* __restrict__ k_o, u16* __restrict__ v_o)
{
    __shared__ __align__(16) u16 lds[16384];   // [A0|A1|B0|B1] 4x8KB -> Ct 32KB
    __shared__ float bs[128];
    const int tid  = threadIdx.x;
    const int lane = tid & 63, w = tid >> 6;
    const int s    = lane & 15, quad = lane >> 4;
    const int bid  = blockIdx.x;
    const int xcd  = bid & 7, j0 = bid >> 3;       // j0 in 0..143
    const int bm   = (xcd * 8 + j0 / 18) * 128;
    const int sub  = j0 % 18;
    const int seg  = sub / 6;
    const int bn   = (sub % 6) * 128;
    const u16* W = (seg == 0) ? W0 : ((seg == 1) ? W1 : W2);
    u16* OUT = (seg == 0) ? q_o : ((seg == 1) ? k_o : v_o);
    const int mh = (w >> 1) * 64, nh = (w & 1) * 64;
    const int wb = tid & ~63;
    const int cq = quad ^ ((s >> 1) & 3);      // swizzled frag chunk

    if (tid < 128)
        bs[tid] = (seg == 1) ? bk[bn + tid] : ((seg == 2) ? bv[bn + tid] : 0.0f);

    f32x4 acc[4][4];   // [j (n-tile)][i (m-tile)], C^T
    #pragma unroll
    for (int j = 0; j < 4; ++j)
        #pragma unroll
        for (int i = 0; i < 4; ++i) acc[j][i] = (f32x4){0.f, 0.f, 0.f, 0.f};

    {
        int c = tid, r = c >> 2, cs = (c & 3) ^ ((r >> 1) & 3);
        gld16(A + (size_t)(bm + r) * D_ + cs * 8, lds + (size_t)wb * 8);
        gld16(W + (size_t)(bn + r) * D_ + cs * 8, lds + 8192 + (size_t)wb * 8);
        c = tid + 256; r = c >> 2; cs = (c & 3) ^ ((r >> 1) & 3);
        gld16(A + (size_t)(bm + r) * D_ + cs * 8, lds + (size_t)(wb + 256) * 8);
        gld16(W + (size_t)(bn + r) * D_ + cs * 8, lds + 8192 + (size_t)(wb + 256) * 8);
    }
    __syncthreads();

    for (int t = 0; t < 24; ++t) {
        const u16* Ab = lds + (t & 1) * 4096;
        const u16* Bb = lds + 8192 + (t & 1) * 4096;
        if (t < 23) {
            const int k0 = (t + 1) * 32;
            u16* Ad = lds + ((t + 1) & 1) * 4096;
            u16* Bd = lds + 8192 + ((t + 1) & 1) * 4096;
            int c = tid, r = c >> 2, cs = (c & 3) ^ ((r >> 1) & 3);
            gld16(A + (size_t)(bm + r) * D_ + k0 + cs * 8, Ad + (size_t)wb * 8);
            gld16(W + (size_t)(bn + r) * D_ + k0 + cs * 8, Bd + (size_t)wb * 8);
            c = tid + 256; r = c >> 2; cs = (c & 3) ^ ((r >> 1) & 3);
            gld16(A + (size_t)(bm + r) * D_ + k0 + cs * 8, Ad + (size_t)(wb + 256) * 8);
            gld16(W + (size_t)(bn + r) * D_ + k0 + cs * 8, Bd + (size_t)(wb + 256) * 8);
        }
        bf16x8 af[4], bf[4];
        #pragma unroll
        for (int i = 0; i < 4; ++i)
            af[i] = *(const bf16x8*)(Ab + (mh + i * 16 + s) * 32 + cq * 8);
        #pragma unroll
        for (int j = 0; j < 4; ++j)
            bf[j] = *(const bf16x8*)(Bb + (nh + j * 16 + s) * 32 + cq * 8);
        #pragma unroll
        for (int j = 0; j < 4; ++j)
            #pragma unroll
            for (int i = 0; i < 4; ++i)
                acc[j][i] = __builtin_amdgcn_mfma_f32_16x16x32_bf16(
                    bf[j], af[i], acc[j][i], 0, 0, 0);   // C^T: rows=n, cols=m
        __syncthreads();
    }
    // epilogue: bf16 + bias -> Ct[m][128] (chunk ^ (m&15)) -> coalesced store
    u16* Ct = lds;
    #pragma unroll
    for (int j = 0; j < 4; ++j) {
        const int n0 = nh + j * 16 + quad * 4;
        const f32x4 b4 = *(const f32x4*)(bs + n0);
        const int cn = n0 >> 3, off = n0 & 7;
        #pragma unroll
        for (int i = 0; i < 4; ++i) {
            const int m = mh + i * 16 + s;
            u16x4 ov;
            #pragma unroll
            for (int r = 0; r < 4; ++r) ov[r] = f2bf(acc[j][i][r] + b4[r]);
            *(u16x4*)(Ct + m * 128 + ((cn ^ (m & 15)) * 8) + off) = ov;
        }
    }
    __syncthreads();
    {
        const int m = tid >> 1, half = tid & 1;
        u16* dst = OUT + (size_t)(bm + m) * D_ + bn + half * 64;
        #pragma unroll
        for (int cc = 0; cc < 8; ++cc) {
            const int cn = half * 8 + cc;
            u16x8 v = *(const u16x8*)(Ct + m * 128 + ((cn ^ (m & 15)) * 8));
            *(u16x8*)(dst + cc * 8) = v;
        }
    }
}

// ---------------------------------------------------------------------------
// Final GEMM: out = ob @ Wo^T + bo + x (fp32 out). 128x128 tile, dbuf, C^T,
// float4 stores. Grid 384 = 8 XCD x (8 bm x 6 bn); (256,3). (r7 64x128
// retile was +7us: halved A-reuse per staging. This r5 version is best.)
// ---------------------------------------------------------------------------
__global__ __launch_bounds__(256, 3) void gemm_final(
    const u16* __restrict__ A, const u16* __restrict__ W,
    const float* __restrict__ bias, const float* __restrict__ resid,
    float* __restrict__ outf)
{
    __shared__ __align__(16) u16 lds[16384];
    const int tid  = threadIdx.x;
    const int lane = tid & 63, w = tid >> 6;
    const int s    = lane & 15, quad = lane >> 4;
    const int bid  = blockIdx.x;
    const int xcd  = bid & 7, j0 = bid >> 3;       // j0 in 0..47
    const int bm   = (xcd * 8 + j0 / 6) * 128;
    const int bn   = (j0 % 6) * 128;
    const int mh   = (w >> 1) * 64, nh = (w & 1) * 64;
    const int wb   = tid & ~63;
    const int cq   = quad ^ ((s >> 1) & 3);
    f32x4 acc[4][4];
    #pragma unroll
    for (int j = 0; j < 4; ++j)
        #pragma unroll
        for (int i = 0; i < 4; ++i) acc[j][i] = (f32x4){0.f, 0.f, 0.f, 0.f};

    {
        int c = tid, r = c >> 2, cs = (c & 3) ^ ((r >> 1) & 3);
        gld16(A + (size_t)(bm + r) * D_ + cs * 8, lds + (size_t)wb * 8);
        gld16(W + (size_t)(bn + r) * D_ + cs * 8, lds + 8192 + (size_t)wb * 8);
        c = tid + 256; r = c >> 2; cs = (c & 3) ^ ((r >> 1) & 3);
        gld16(A + (size_t)(bm + r) * D_ + cs * 8, lds + (size_t)(wb + 256) * 8);
        gld16(W + (size_t)(bn + r) * D_ + cs * 8, lds + 8192 + (size_t)(wb + 256) * 8);
    }
    __syncthreads();

    for (int t = 0; t < 24; ++t) {
        const u16* Ab = lds + (t & 1) * 4096;
        const u16* Bb = lds + 8192 + (t & 1) * 4096;
        if (t < 23) {
            const int k0 = (t + 1) * 32;
            u16* Ad = lds + ((t + 1) & 1) * 4096;
            u16* Bd = lds + 8192 + ((t + 1) & 1) * 4096;
            int c = tid, r = c >> 2, cs = (c & 3) ^ ((r >> 1) & 3);
            gld16(A + (size_t)(bm + r) * D_ + k0 + cs * 8, Ad + (size_t)wb * 8);
            gld16(W + (size_t)(bn + r) * D_ + k0 + cs * 8, Bd + (size_t)wb * 8);
            c = tid + 256; r = c >> 2; cs = (c & 3) ^ ((r >> 1) & 3);
            gld16(A + (size_t)(bm + r) * D_ + k0 + cs * 8, Ad + (size_t)(wb + 256) * 8);
            gld16(W + (size_t)(bn + r) * D_ + k0 + cs * 8, Bd + (size_t)(wb + 256) * 8);
        }
        bf16x8 af[4], bf[4];
        #pragma unroll
        for (int i = 0; i < 4; ++i)
            af[i] = *(const bf16x8*)(Ab + (mh + i * 16 + s) * 32 + cq * 8);
        #pragma unroll
        for (int j = 0; j < 4; ++j)
            bf[j] = *(const bf16x8*)(Bb + (nh + j * 16 + s) * 32 + cq * 8);
        #pragma unroll
        for (int j = 0; j < 4; ++j)
            #pragma unroll
            for (int i = 0; i < 4; ++i)
                acc[j][i] = __builtin_amdgcn_mfma_f32_16x16x32_bf16(
                    bf[j], af[i], acc[j][i], 0, 0, 0);
        __syncthreads();
    }
    #pragma unroll
    for (int j = 0; j < 4; ++j) {
        const int n0 = nh + j * 16 + quad * 4;
        const float4 b4 = *(const float4*)(bias + bn + n0);
        #pragma unroll
        for (int i = 0; i < 4; ++i) {
            const int m = mh + i * 16 + s;
            const size_t base = (size_t)(bm + m) * D_ + bn + n0;
            const float4 rs = *(const float4*)(resid + base);
            float4 o;
            o.x = acc[j][i][0] + b4.x + rs.x;
            o.y = acc[j][i][1] + b4.y + rs.y;
            o.z = acc[j][i][2] + b4.z + rs.z;
            o.w = acc[j][i][3] + b4.w + rs.w;
            *(float4*)(outf + base) = o;
        }
    }
}

// ---------------------------------------------------------------------------
// Row LayerNorm (pop var, eps 1e-5) * gamma * scale, bf16 in -> bf16 out.
// VECTORIZED (G13): 8 rows/block, 32 lanes/row, 3x u16x8 per lane (24 elems),
// 32-lane shfl_xor reduce (no LDS). Both q (SC2) and k in one launch (grid.y).
// ---------------------------------------------------------------------------
__global__ __launch_bounds__(256) void ln2_bf16(
    const u16* __restrict__ Q, const u16* __restrict__ K,
    const float* __restrict__ gq, const float* __restrict__ gk,
    u16* __restrict__ Yq, u16* __restrict__ Yk)
{
    const int which = blockIdx.y;
    const int rowi  = threadIdx.x >> 5;          // 0..7
    const int l32   = threadIdx.x & 31;
    const int row   = blockIdx.x * 8 + rowi;
    const u16* x = (which ? K : Q) + (size_t)row * D_ + l32 * 24;
    const float* gamma = (which ? gk : gq) + l32 * 24;
    u16* Y = (which ? Yk : Yq) + (size_t)row * D_ + l32 * 24;
    const float scale = which ? 1.0f : (float)SC2;

    u16x8 vv[3];
    float f[24];
    float lsum = 0.f, lsq = 0.f;
    #pragma unroll
    for (int e = 0; e < 3; ++e) {
        vv[e] = *(const u16x8*)(x + e * 8);
        #pragma unroll
        for (int k = 0; k < 8; ++k) {
            float t = bf2f(vv[e][k]);
            f[e * 8 + k] = t; lsum += t; lsq += t * t;
        }
    }
    #pragma unroll
    for (int off = 16; off > 0; off >>= 1) {     // 32-lane group reduce
        lsum += __shfl_xor(lsum, off);
        lsq  += __shfl_xor(lsq,  off);
    }
    const float mu  = lsum * (1.0f / D_);
    const float var = lsq * (1.0f / D_) - mu * mu;
    const float inv = rsqrtf(var + 1e-5f) * scale;
    #pragma unroll
    for (int e = 0; e < 3; ++e) {
        const float4 ga = *(const float4*)(gamma + e * 8);
        const float4 gb = *(const float4*)(gamma + e * 8 + 4);
        u16x8 o;
        o[0] = f2bf((f[e*8+0] - mu) * inv * ga.x);
        o[1] = f2bf((f[e*8+1] - mu) * inv * ga.y);
        o[2] = f2bf((f[e*8+2] - mu) * inv * ga.z);
        o[3] = f2bf((f[e*8+3] - mu) * inv * ga.w);
        o[4] = f2bf((f[e*8+4] - mu) * inv * gb.x);
        o[5] = f2bf((f[e*8+5] - mu) * inv * gb.y);
        o[6] = f2bf((f[e*8+6] - mu) * inv * gb.z);
        o[7] = f2bf((f[e*8+7] - mu) * inv * gb.w);
        *(u16x8*)(Y + e * 8) = o;
    }
}

// ---------------------------------------------------------------------------
// Pass A: per-key l = sum_q exp2(s~[q,k]) (NO max: QK-norm bounds scores).
// r5 structure (best total): 128q tiles, single acc[4][4], Qs dbuf, setprio.
// V-transpose (+1/l fold, PV key-permutation) FUSED at end, reusing Qs[0]
// as Ts; normalizers stay in LDS (rls). 768 = 8 XCD x (6 bh x 16 k-blocks).
// ---------------------------------------------------------------------------
__global__ __launch_bounds__(256, 3) void attn_stats(
    const u16* __restrict__ Qb, const u16* __restrict__ Kb,
    const u16* __restrict__ Vb, u16* __restrict__ Vt)
{
    __shared__ __align__(16) u16 Ks[128 * 64];       // 16 KB
    __shared__ __align__(16) u16 Qs[2][128 * 64];    // 32 KB dbuf (-> Ts)
    __shared__ float lbuf[4][64];
    __shared__ float rls[128];
    const int tid  = threadIdx.x;
    const int lane = tid & 63, w = tid >> 6;
    const int s    = lane & 15, quad = lane >> 4;
    const int s7   = s & 7;
    const int bid  = blockIdx.x;
    const int xcd  = bid & 7, j0 = bid >> 3;       // j0 in 0..95
    const int bh   = xcd * 6 + j0 / 16;
    const int kbase = (j0 % 16) * 128;
    const int b    = bh / NH_, h = bh % NH_;
    const u16* Qg = Qb + (size_t)b * L_ * D_ + h * HD_;
    const u16* Kg = Kb + (size_t)b * L_ * D_ + h * HD_;
    const int mh = (w >> 1) * 64;   // key half
    const int nh = (w & 1) * 64;    // query half
    const int wb = tid & ~63;

    #pragma unroll
    for (int c0 = 0; c0 < 1024; c0 += 256) {
        int c = c0 + tid, r = c >> 3, cc = (c & 7) ^ (r & 7);
        gld16(Kg + (size_t)(kbase + r) * D_ + cc * 8, Ks + (size_t)(c0 + wb) * 8);
        gld16(Qg + (size_t)r * D_ + cc * 8, Qs[0] + (size_t)(c0 + wb) * 8);
    }
    __syncthreads();
    bf16x8 kf[2][4];
    #pragma unroll
    for (int kk = 0; kk < 2; ++kk)
        #pragma unroll
        for (int i = 0; i < 4; ++i)
            kf[kk][i] = *(const bf16x8*)(Ks + (mh + i * 16 + s) * 64 +
                                         ((kk * 4 + quad) ^ s7) * 8);
    float lacc[4][4];
    #pragma unroll
    for (int i = 0; i < 4; ++i)
        #pragma unroll
        for (int r = 0; r < 4; ++r) lacc[i][r] = 0.f;

    for (int t = 0; t < 16; ++t) {
        if (t < 15) {
            const int qn = (t + 1) * 128;
            u16* Qd = Qs[(t + 1) & 1];
            #pragma unroll
            for (int c0 = 0; c0 < 1024; c0 += 256) {
                int c = c0 + tid, r = c >> 3, cc = (c & 7) ^ (r & 7);
                gld16(Qg + (size_t)(qn + r) * D_ + cc * 8, Qd + (size_t)(c0 + wb) * 8);
            }
        }
        const u16* Qt = Qs[t & 1];
        f32x4 acc[4][4];
        #pragma unroll
        for (int i = 0; i < 4; ++i)
            #pragma unroll
            for (int j = 0; j < 4; ++j) acc[i][j] = (f32x4){0.f, 0.f, 0.f, 0.f};
        #pragma unroll
        for (int kk = 0; kk < 2; ++kk) {
            bf16x8 bf[4];
            #pragma unroll
            for (int j = 0; j < 4; ++j)
                bf[j] = *(const bf16x8*)(Qt + (nh + j * 16 + s) * 64 +
                                         ((kk * 4 + quad) ^ s7) * 8);
            __builtin_amdgcn_s_setprio(1);
            #pragma unroll
            for (int i = 0; i < 4; ++i)
                #pragma unroll
                for (int j = 0; j < 4; ++j)
                    acc[i][j] = __builtin_amdgcn_mfma_f32_16x16x32_bf16(
                        kf[kk][i], bf[j], acc[i][j], 0, 0, 0);
            __builtin_amdgcn_s_setprio(0);
        }
        #pragma unroll
        for (int i = 0; i < 4; ++i)
            #pragma unroll
            for (int r = 0; r < 4; ++r) {
                float l0 = ex2(acc[i][0][r]) + ex2(acc[i][1][r]);
                float l1 = ex2(acc[i][2][r]) + ex2(acc[i][3][r]);
                lacc[i][r] += l0 + l1;
            }
        __syncthreads();
    }
    #pragma unroll
    for (int i = 0; i < 4; ++i)
        #pragma unroll
        for (int r = 0; r < 4; ++r) {
            float v = lacc[i][r];
            #pragma unroll
            for (int d2 = 1; d2 < 16; d2 <<= 1) v += __shfl_xor(v, d2);
            lacc[i][r] = v;
        }
    if (s == 0) {
        #pragma unroll
        for (int i = 0; i < 4; ++i)
            #pragma unroll
            for (int r = 0; r < 4; ++r)
                lbuf[w][i * 16 + quad * 4 + r] = lacc[i][r];
    }
    __syncthreads();
    if (tid < 128) {
        int kh = tid >> 6, kl = tid & 63;
        float l = lbuf[kh * 2][kl] + lbuf[kh * 2 + 1][kl];
        rls[tid] = 1.0f / l;
    }
    __syncthreads();

    // ---- fused V transpose: scale by 1/l, PV key-permutation, 2 x 64 rows.
    // Ts reuses Qs[0] (dead after t=15; barriers above order the reuse).
    u16 (*Ts)[72] = (u16 (*)[72])(&Qs[0][0]);
    for (int half = 0; half < 2; ++half) {
        const int l0g = kbase + half * 64;
        for (int c = tid; c < 512; c += 256) {
            int r = c >> 3, cc = c & 7;
            u16x8 val = *(const u16x8*)(Vb + (size_t)(b * L_ + l0g + r) * D_ +
                                        h * HD_ + cc * 8);
            const float rl = rls[half * 64 + r];
            #pragma unroll
            for (int e = 0; e < 8; ++e) val[e] = f2bf(bf2f(val[e]) * rl);
            *(u16x8*)(&Ts[r][cc * 8]) = val;
        }
        __syncthreads();
        const int d = tid >> 2, lc = (tid & 3) * 16;
        u16 tmp[16];
        #pragma unroll
        for (int e = 0; e < 16; ++e) tmp[e] = Ts[lc + e][d];
        u16* dst = Vt + ((size_t)bh * HD_ + d) * L_ + l0g + (lc & 32) +
                   ((lc >> 4) & 1) * 4;
        #pragma unroll
        for (int qd = 0; qd < 4; ++qd) {
            u16x4 o;
            #pragma unroll
            for (int e = 0; e < 4; ++e) o[e] = tmp[qd * 4 + e];
            *(u16x4*)(dst + qd * 8) = o;
        }
        __syncthreads();
    }
}

// ---------------------------------------------------------------------------
// Pass B: O^T = V'^T · P^T, P = exp2(s~) in registers. 128 q/block,
// wave = 64 keys x 32-q slice. CROSS-TILE SOFTWARE PIPELINE:
//   iter t:  prefetch(t+2) | exp(t)->pk | S-MFMA(t+1) [indep of exp(t)]
//            | PV-MFMA(t)  | vmcnt(2)+barrier
// Two acc_s states (static names, rule-#20 safe) alternate via unroll-by-2.
// Stage order per tile: K x2 then V x2 -> steady-state wait = vmcnt(2)
// (drains V(t+1)+K(t+2), leaves V(t+2) in flight). Triple-buffered K/V.
// setprio only around PV (S cluster left free for exp interleave).
// ---------------------------------------------------------------------------
__global__ __launch_bounds__(256, 3) void attn_out(
    const u16* __restrict__ Qb, const u16* __restrict__ Kb,
    const u16* __restrict__ Vt, u16* __restrict__ Ob)
{
    __shared__ __align__(16) u16 Ks[3][64 * 64];   // 24 KB triple-buffer
    __shared__ __align__(16) u16 Vts[3][64 * 64];  // 24 KB triple-buffer
    const int tid  = threadIdx.x;
    const int lane = tid & 63, w = tid >> 6;
    const int s    = lane & 15, quad = lane >> 4;
    const int s7   = s & 7;
    const int bid  = blockIdx.x;
    const int xcd  = bid & 7, j0 = bid >> 3;       // j0 in 0..95
    const int bh   = xcd * 6 + j0 / 16;
    const int qbase = (j0 % 16) * 128;
    const int b    = bh / NH_, h = bh % NH_;
    const int qw   = w * 32;                        // this wave's 32-q slice
    const u16* Qg = Qb + (size_t)b * L_ * D_ + h * HD_;
    const u16* Kg = Kb + (size_t)b * L_ * D_ + h * HD_;
    const u16* Vg = Vt + (size_t)bh * HD_ * L_;
    const int wb = tid & ~63;

    // Q frags direct global->reg (oldest in vm queue; drained by prologue wait)
    bf16x8 qf[2][2];
    #pragma unroll
    for (int kk = 0; kk < 2; ++kk)
        #pragma unroll
        for (int j = 0; j < 2; ++j)
            qf[kk][j] = *(const bf16x8*)(
                Qg + (size_t)(qbase + qw + j * 16 + s) * D_ + (kk * 4 + quad) * 8);

    // stage K0,K1 then V0,V1 (queue order: drain thru V0+K1, leave V1 x2)
    {
        int c = tid, r = c >> 3, cc = (c & 7) ^ (r & 7);
        int c2 = tid + 256, r2 = c2 >> 3, cc2 = (c2 & 7) ^ (r2 & 7);
        gld16(Kg + (size_t)r * D_ + cc * 8,          Ks[0] + (size_t)wb * 8);
        gld16(Kg + (size_t)r2 * D_ + cc2 * 8,        Ks[0] + (size_t)(wb + 256) * 8);
        gld16(Kg + (size_t)(64 + r) * D_ + cc * 8,   Ks[1] + (size_t)wb * 8);
        gld16(Kg + (size_t)(64 + r2) * D_ + cc2 * 8, Ks[1] + (size_t)(wb + 256) * 8);
        gld16(Vg + (size_t)r * L_ + cc * 8,          Vts[0] + (size_t)wb * 8);
        gld16(Vg + (size_t)r2 * L_ + cc2 * 8,        Vts[0] + (size_t)(wb + 256) * 8);
        gld16(Vg + (size_t)r * L_ + 64 + cc * 8,     Vts[1] + (size_t)wb * 8);
        gld16(Vg + (size_t)r2 * L_ + 64 + cc2 * 8,   Vts[1] + (size_t)(wb + 256) * 8);
    }
    asm volatile("s_waitcnt vmcnt(2)" ::: "memory");   // leave V1 x2 in flight
    __builtin_amdgcn_s_barrier();

    f32x4 acc_o[4][2];
    #pragma unroll
    for (int i = 0; i < 4; ++i)
        #pragma unroll
        for (int j = 0; j < 2; ++j) acc_o[i][j] = (f32x4){0.f, 0.f, 0.f, 0.f};

    // ---- prologue: S(0) -> acc_s0 ----
    f32x4 acc_s0[4][2], acc_s1[4][2];
    #pragma unroll
    for (int i = 0; i < 4; ++i)
        #pragma unroll
        for (int j = 0; j < 2; ++j) acc_s0[i][j] = (f32x4){0.f, 0.f, 0.f, 0.f};
    #pragma unroll
    for (int kk = 0; kk < 2; ++kk) {
        bf16x8 kfr[4];
        #pragma unroll
        for (int i = 0; i < 4; ++i)
            kfr[i] = *(const bf16x8*)(Ks[0] + (i * 16 + s) * 64 +
                                      ((kk * 4 + quad) ^ s7) * 8);
        #pragma unroll
        for (int i = 0; i < 4; ++i)
            #pragma unroll
            for (int j = 0; j < 2; ++j)
                acc_s0[i][j] = __builtin_amdgcn_mfma_f32_16x16x32_bf16(
                    kfr[i], qf[kk][j], acc_s0[i][j], 0, 0, 0);
    }

// Tile body. ACCC: acc_s state holding S(TT). ACCN: state to fill with S(TT+1).
// DO_PF: prefetch tile TT+2.  DO_S: compute S(TT+1).  WMODE: 2 / 0 / -1.
#define ATTN_TILE(ACCC, ACCN, TT, DO_PF, DO_S, WMODE)                          \
    do {                                                                       \
        const int t_ = (TT);                                                   \
        if (DO_PF) {                                                           \
            const int pi_ = (t_ + 2) % 3;                                      \
            const int kn_ = (t_ + 2) * 64;                                     \
            u16* Kd_ = Ks[pi_]; u16* Vd_ = Vts[pi_];                           \
            int c_ = tid, r_ = c_ >> 3, cc_ = (c_ & 7) ^ (r_ & 7);             \
            int c2_ = tid + 256, r2_ = c2_ >> 3, cc2_ = (c2_ & 7) ^ (r2_ & 7); \
            gld16(Kg + (size_t)(kn_ + r_) * D_ + cc_ * 8,                      \
                  Kd_ + (size_t)wb * 8);                                       \
            gld16(Kg + (size_t)(kn_ + r2_) * D_ + cc2_ * 8,                    \
                  Kd_ + (size_t)(wb + 256) * 8);                               \
            gld16(Vg + (size_t)r_ * L_ + kn_ + cc_ * 8,                        \
                  Vd_ + (size_t)wb * 8);                                       \
            gld16(Vg + (size_t)r2_ * L_ + kn_ + cc2_ * 8,                      \
                  Vd_ + (size_t)(wb + 256) * 8);                               \
        }                                                                      \
        /* exp(TT): ACCC -> pk (VALU; independent of S(TT+1) MFMAs) */         \
        unsigned pk_[4][2][2];                                                 \
        _Pragma("unroll")                                                      \
        for (int i = 0; i < 4; ++i)                                            \
            _Pragma("unroll")                                                  \
            for (int j = 0; j < 2; ++j) {                                      \
                float p0_ = ex2(ACCC[i][j][0]), p1_ = ex2(ACCC[i][j][1]);      \
                float p2_ = ex2(ACCC[i][j][2]), p3_ = ex2(ACCC[i][j][3]);      \
                pk_[i][j][0] = packbf(p0_, p1_);                               \
                pk_[i][j][1] = packbf(p2_, p3_);                               \
            }                                                                  \
        if (DO_S) {                                                            \
            const u16* Kt_ = Ks[(t_ + 1) % 3];                                 \
            _Pragma("unroll")                                                  \
            for (int i = 0; i < 4; ++i)                                        \
                _Pragma("unroll")                                              \
                for (int j = 0; j < 2; ++j)                                    \
                    ACCN[i][j] = (f32x4){0.f, 0.f, 0.f, 0.f};                  \
            _Pragma("unroll")                                                  \
            for (int kk = 0; kk < 2; ++kk) {                                   \
                bf16x8 kfr_[4];                                                \
                _Pragma("unroll")                                              \
                for (int i = 0; i < 4; ++i)                                    \
                    kfr_[i] = *(const bf16x8*)(Kt_ + (i * 16 + s) * 64 +       \
                                               ((kk * 4 + quad) ^ s7) * 8);    \
                _Pragma("unroll")                                              \
                for (int i = 0; i < 4; ++i)                                    \
                    _Pragma("unroll")                                          \
                    for (int j = 0; j < 2; ++j)                                \
                        ACCN[i][j] = __builtin_amdgcn_mfma_f32_16x16x32_bf16(  \
                            kfr_[i], qf[kk][j], ACCN[i][j], 0, 0, 0);          \
            }                                                                  \
        }                                                                      \
        /* PV(TT) */                                                           \
        {                                                                      \
            const u16* Vtt_ = Vts[t_ % 3];                                     \
            _Pragma("unroll")                                                  \
            for (int kk = 0; kk < 2; ++kk) {                                   \
                bf16x8 av_[4];                                                 \
                _Pragma("unroll")                                              \
                for (int i = 0; i < 4; ++i)                                    \
                    av_[i] = *(const bf16x8*)(Vtt_ + (i * 16 + s) * 64 +       \
                                              ((kk * 4 + quad) ^ s7) * 8);     \
                __builtin_amdgcn_s_setprio(1);                                 \
                _Pragma("unroll")                                              \
                for (int j = 0; j < 2; ++j) {                                  \
                    union { unsigned u[4]; bf16x8 v; } bu_;                    \
                    bu_.u[0] = pk_[2 * kk][j][0];                              \
                    bu_.u[1] = pk_[2 * kk][j][1];                              \
                    bu_.u[2] = pk_[2 * kk + 1][j][0];                          \
                    bu_.u[3] = pk_[2 * kk + 1][j][1];                          \
                    _Pragma("unroll")                                          \
                    for (int i = 0; i < 4; ++i)                                \
                        acc_o[i][j] = __builtin_amdgcn_mfma_f32_16x16x32_bf16( \
                            av_[i], bu_.v, acc_o[i][j], 0, 0, 0);              \
                }                                                              \
                __builtin_amdgcn_s_setprio(0);                                 \
            }                                                                  \
        }                                                                      \
        if (WMODE == 2) {                                                      \
            asm volatile("s_waitcnt vmcnt(2)" ::: "memory");                   \
            __builtin_amdgcn_s_barrier();                                      \
        } else if (WMODE == 0) {                                               \
            asm volatile("s_waitcnt vmcnt(0)" ::: "memory");                   \
            __builtin_amdgcn_s_barrier();                                      \
        }                                                                      \
    } while (0)

    for (int t = 0; t < 30; t += 2) {
        ATTN_TILE(acc_s0, acc_s1, t,     1, 1, 2);
        ATTN_TILE(acc_s1, acc_s0, t + 1, 1, 1, 2);
    }
    ATTN_TILE(acc_s0, acc_s1, 30, 0, 1, 0);   // no prefetch; drain; S(31)
    ATTN_TILE(acc_s1, acc_s0, 31, 0, 0, -1);  // tail: exp(31)+PV(31) only
#undef ATTN_TILE

    __syncthreads();
    // ---- epilogue: O^T -> Ks[0..1] as [128 q][64 d] (swizzled) -> store
    u16* Ep = (u16*)Ks;
    #pragma unroll
    for (int i = 0; i < 4; ++i) {
        const int dchunk = i * 2 + (quad >> 1), doff = (quad & 1) * 4;
        #pragma unroll
        for (int j = 0; j < 2; ++j) {
            const int q = qw + j * 16 + s;
            u16x4 ov;
            #pragma unroll
            for (int r = 0; r < 4; ++r) ov[r] = f2bf(acc_o[i][j][r]);
            *(u16x4*)(Ep + q * 64 + (dchunk ^ s7) * 8 + doff) = ov;
        }
    }
    __syncthreads();
    {
        const int q = tid >> 1, half = tid & 1, q7 = q & 7;
        u16* dst = Ob + (size_t)(b * L_ + qbase + q) * D_ + h * HD_ + half * 32;
        #pragma unroll
        for (int c = 0; c < 4; ++c) {
            const int cn = half * 4 + c;
            u16x8 v = *(const u16x8*)(Ep + q * 64 + ((cn ^ q7) * 8));
            *(u16x8*)(dst + c * 8) = v;
        }
    }
}

// ---------------------------------------------------------------------------
extern "C" void kernel_launch(void* const* d_in, const int* in_sizes, int n_in,
                              void* d_out, int out_size, void* d_ws, size_t ws_size,
                              hipStream_t stream)
{
    const float* x  = (const float*)d_in[0];
    const float* Wq = (const float*)d_in[1];
    const float* Wk = (const float*)d_in[2];
    const float* bk = (const float*)d_in[3];
    const float* Wv = (const float*)d_in[4];
    const float* bv = (const float*)d_in[5];
    const float* gq = (const float*)d_in[6];
    const float* gk = (const float*)d_in[7];
    const float* Wo = (const float*)d_in[8];
    const float* bo = (const float*)d_in[9];
    float* out = (float*)d_out;

    char* p = (char*)d_ws;
    u16* xb   = (u16*)p;  p += (size_t)M_ * D_ * 2;
    u16* qpre = (u16*)p;  p += (size_t)M_ * D_ * 2;   // ob aliases after LN
    u16* kpre = (u16*)p;  p += (size_t)M_ * D_ * 2;   // vt aliases after LN
    u16* vb   = (u16*)p;  p += (size_t)M_ * D_ * 2;
    u16* qb   = (u16*)p;  p += (size_t)M_ * D_ * 2;
    u16* kb   = (u16*)p;  p += (size_t)M_ * D_ * 2;
    u16* wqb  = (u16*)p;  p += (size_t)D_ * D_ * 2;
    u16* wkb  = (u16*)p;  p += (size_t)D_ * D_ * 2;
    u16* wvb  = (u16*)p;  p += (size_t)D_ * D_ * 2;
    u16* wob  = (u16*)p;  p += (size_t)D_ * D_ * 2;
    u16* ob = qpre;   // dead after LN
    u16* vt = kpre;   // dead after LN

    const int nTot8 = (M_ * D_ + 4 * D_ * D_) / 8;    // 1,081,344
    cvt_all<<<(nTot8 + 255) / 256, 256, 0, stream>>>(
        x, Wq, Wk, Wv, Wo, xb, wqb, wkb, wvb, wob);

    gemm_qkv<<<1152, 256, 0, stream>>>(
        xb, wqb, wkb, wvb, bk, bv, qpre, kpre, vb);

    ln2_bf16<<<dim3(M_ / 8, 2), 256, 0, stream>>>(qpre, kpre, gq, gk, qb, kb);

    attn_stats<<<768, 256, 0, stream>>>(qb, kb, vb, vt);   // + fused V-transpose
    attn_out<<<768, 256, 0, stream>>>(qb, kb, vt, ob);

    gemm_final<<<384, 256, 0, stream>>>(ob, wob, bo, x, out);
}